// Round 4
// baseline (126.020 us; speedup 1.0000x reference)
//
#include <hip/hip_runtime.h>

#define D 300
#define KP 328          // padded K stride (elements); 656 B rows, 4-bank stagger
#define KSTEPS 10       // 320 / 32
#define WPB 128         // words per block
#define ROWS 256        // X rows per block
#define NSEG 41         // CHUNK_BYTES / 1024
#define CHUNK_BYTES 41984
#define HALF_BYTES 20992
#define NCHUNK 24       // 16 QK chunks (32 Q cols + 32 K cols) + 8 V chunks (64 cols)

typedef __attribute__((ext_vector_type(4))) float f32x4;
typedef __attribute__((ext_vector_type(8))) short bf16x8;

__device__ inline unsigned short f2bf(float f) {
  unsigned int u = __float_as_uint(f);
  unsigned int r = (u + 0x7fffu + ((u >> 16) & 1u)) >> 16;
  return (unsigned short)r;
}

__device__ inline void gload_lds16(const void* g, void* l) {
  __builtin_amdgcn_global_load_lds(
      (const __attribute__((address_space(1))) unsigned int*)g,
      (__attribute__((address_space(3))) unsigned int*)l, 16, 0, 0);
}

// wt[n][k] = W[k][n&511] bf16; rows 0-511=Wq, 512-1023=Wk, 1024-1535=Wv; k>=300 zero
__global__ __launch_bounds__(512) void prep_weights(
    const float* __restrict__ Wq, const float* __restrict__ Wk,
    const float* __restrict__ Wv, unsigned short* __restrict__ wt) {
  int idx = blockIdx.x * 512 + threadIdx.x;
  if (idx >= 1536 * KP) return;
  int n = idx / KP, k = idx - n * KP;
  const float* src = (n < 512) ? Wq : ((n < 1024) ? Wk : Wv);
  int col = n & 511;
  float v = (k < D) ? src[k * 512 + col] : 0.0f;
  wt[idx] = f2bf(v);
}

__global__ __launch_bounds__(512, 2) void fused_attn(
    const float* __restrict__ charv, const float* __restrict__ wordv,
    const unsigned short* __restrict__ wt,
    const float* __restrict__ bk, const float* __restrict__ bq,
    const float* __restrict__ bv, float* __restrict__ out) {
  extern __shared__ char lds[];
  float* biasL = (float*)(lds + 2 * CHUNK_BYTES);  // [1536]
  float* sS    = biasL + 1536;                     // [2 cg][128 w][4]
  float* sAt   = sS + 1024;                        // [128 w][4]

  const int tid  = threadIdx.x;
  const int wid  = tid >> 6;
  const int lane = tid & 63;
  const int lrow = lane & 15;
  const int kgrp = lane >> 4;
  const int rg   = wid >> 1;   // 0..3 : rows rg*64 .. +64
  const int cg   = wid & 1;    // 0..1 : col half of each chunk

  // chunk t: 0..15 = [Q_g(32 cols) | K_g(32 cols)], g=t ; 16..23 = V 64-col chunk
  auto stage = [&](int t) {
    const char* p0;
    const char* p1;
    int split;
    if (t < 16) {
      p0 = (const char*)(wt + t * 32 * KP);
      p1 = (const char*)(wt + (512 + t * 32) * KP) - HALF_BYTES;
      split = HALF_BYTES;
    } else {
      p0 = (const char*)(wt + (1024 + (t - 16) * 64) * KP);
      p1 = p0;
      split = 1 << 30;
    }
    char* dst = lds + (t & 1) * CHUNK_BYTES;
    for (int j = wid; j < NSEG; j += 8) {
      int b = j * 1024 + lane * 16;
      const char* src = (b < split) ? p0 : p1;   // per-lane global src is legal
      gload_lds16(src + b, dst + j * 1024);
    }
  };

  // ---- prologue: stage chunk 0, biases -> LDS, X fragments global -> regs (bf16)
  stage(0);
  for (int i = tid; i < 1536; i += 512) {
    float v = (i < 512) ? bq[i] : ((i < 1024) ? bk[i - 512] : bv[i - 1024]);
    biasL[i] = v;
  }

  bf16x8 a[4][KSTEPS];
#pragma unroll
  for (int rt = 0; rt < 4; ++rt) {
    int row = blockIdx.x * ROWS + rg * 64 + rt * 16 + lrow;
    const float* rp = ((row & 1) ? charv : wordv) + (row >> 1) * D;
#pragma unroll
    for (int ks = 0; ks < KSTEPS; ++ks) {
      int k0 = ks * 32 + kgrp * 8;
      float4 lo = {0.f, 0.f, 0.f, 0.f}, hi = {0.f, 0.f, 0.f, 0.f};
      if (k0 + 8 <= D) {
        lo = *(const float4*)(rp + k0);
        hi = *(const float4*)(rp + k0 + 4);
      } else if (k0 < D) {
        lo = *(const float4*)(rp + k0);
      }
      bf16x8 v;
      v[0] = (short)f2bf(lo.x); v[1] = (short)f2bf(lo.y);
      v[2] = (short)f2bf(lo.z); v[3] = (short)f2bf(lo.w);
      v[4] = (short)f2bf(hi.x); v[5] = (short)f2bf(hi.y);
      v[6] = (short)f2bf(hi.z); v[7] = (short)f2bf(hi.w);
      a[rt][ks] = v;
    }
  }
  __syncthreads();  // chunk 0 landed, biases visible

  float p[4][8];
#pragma unroll
  for (int rt = 0; rt < 4; ++rt)
#pragma unroll
    for (int t = 0; t < 8; ++t) p[rt][t] = 0.f;

  // ---- Phase A: 16 QK chunks, 2-phase pipeline
  for (int t = 0; t < 16; ++t) {
    stage(t + 1);
    const unsigned short* bufp = (const unsigned short*)(lds + (t & 1) * CHUNK_BYTES);
    float bqv = biasL[t * 32 + cg * 16 + lrow];
    float bkv = biasL[512 + t * 32 + cg * 16 + lrow];
    f32x4 accQ[4], accK[4];
#pragma unroll
    for (int rt = 0; rt < 4; ++rt) {
      accQ[rt] = (f32x4){bqv, bqv, bqv, bqv};
      accK[rt] = (f32x4){bkv, bkv, bkv, bkv};
    }
    const unsigned short* pq = bufp + (cg * 16 + lrow) * KP + kgrp * 8;
#pragma unroll
    for (int ks = 0; ks < KSTEPS; ++ks) {
      bf16x8 b0 = *(const bf16x8*)(pq + ks * 32);             // Q cols
      bf16x8 b1 = *(const bf16x8*)(pq + 32 * KP + ks * 32);   // K cols
#pragma unroll
      for (int rt = 0; rt < 4; ++rt) {
        accQ[rt] = __builtin_amdgcn_mfma_f32_16x16x32_bf16(a[rt][ks], b0, accQ[rt], 0, 0, 0);
        accK[rt] = __builtin_amdgcn_mfma_f32_16x16x32_bf16(a[rt][ks], b1, accK[rt], 0, 0, 0);
      }
    }
    // lane-local score partials (same lane holds Q and K for same (word,col))
#pragma unroll
    for (int rt = 0; rt < 4; ++rt)
#pragma unroll
      for (int wl = 0; wl < 2; ++wl)
#pragma unroll
        for (int i = 0; i < 2; ++i)
#pragma unroll
          for (int j = 0; j < 2; ++j)
            p[rt][wl * 4 + i * 2 + j] += accQ[rt][wl * 2 + i] * accK[rt][wl * 2 + j];
    __syncthreads();
  }

  // ---- scores: reduce over 16 col-lanes, combine cg halves, softmax
#pragma unroll
  for (int rt = 0; rt < 4; ++rt)
#pragma unroll
    for (int t = 0; t < 8; ++t) {
      float v = p[rt][t];
      v += __shfl_xor(v, 1);
      v += __shfl_xor(v, 2);
      v += __shfl_xor(v, 4);
      v += __shfl_xor(v, 8);
      p[rt][t] = v;
    }
  if (lrow == 0) {
#pragma unroll
    for (int rt = 0; rt < 4; ++rt)
#pragma unroll
      for (int t = 0; t < 8; ++t) {
        int w = rg * 32 + rt * 8 + kgrp * 2 + (t >> 2);
        sS[cg * 512 + w * 4 + (t & 3)] = p[rt][t];
      }
  }
  __syncthreads();
  if (tid < 128) {
    const float sc = 0.044194173824159216f;  // 1/sqrt(512)
    float s[4];
#pragma unroll
    for (int t = 0; t < 4; ++t) s[t] = (sS[tid * 4 + t] + sS[512 + tid * 4 + t]) * sc;
#pragma unroll
    for (int i = 0; i < 2; ++i) {
      float m  = fmaxf(s[i * 2], s[i * 2 + 1]);
      float e0 = expf(s[i * 2] - m), e1 = expf(s[i * 2 + 1] - m);
      float inv = 1.0f / (e0 + e1);
      sAt[tid * 4 + i * 2]     = e0 * inv;
      sAt[tid * 4 + i * 2 + 1] = e1 * inv;
    }
  }
  __syncthreads();

  float at0[4][4], at1[4][4];
#pragma unroll
  for (int rt = 0; rt < 4; ++rt) {
    int wA = rg * 32 + rt * 8 + kgrp * 2;
#pragma unroll
    for (int t = 0; t < 4; ++t) {
      at0[rt][t] = sAt[wA * 4 + t];
      at1[rt][t] = sAt[(wA + 1) * 4 + t];
    }
  }

  // ---- Phase B: 8 V chunks + attention combine
  for (int t = 16; t < 24; ++t) {
    if (t + 1 < 24) stage(t + 1);
    const unsigned short* bufp = (const unsigned short*)(lds + (t & 1) * CHUNK_BYTES);
    const int g = t - 16;
    f32x4 accV[4][2];
#pragma unroll
    for (int ct = 0; ct < 2; ++ct) {
      float b = biasL[1024 + g * 64 + cg * 32 + ct * 16 + lrow];
#pragma unroll
      for (int rt = 0; rt < 4; ++rt) accV[rt][ct] = (f32x4){b, b, b, b};
    }
    const unsigned short* pv = bufp + (cg * 32 + lrow) * KP + kgrp * 8;
#pragma unroll
    for (int ks = 0; ks < KSTEPS; ++ks) {
      bf16x8 b0 = *(const bf16x8*)(pv + ks * 32);
      bf16x8 b1 = *(const bf16x8*)(pv + 16 * KP + ks * 32);
#pragma unroll
      for (int rt = 0; rt < 4; ++rt) {
        accV[rt][0] = __builtin_amdgcn_mfma_f32_16x16x32_bf16(a[rt][ks], b0, accV[rt][0], 0, 0, 0);
        accV[rt][1] = __builtin_amdgcn_mfma_f32_16x16x32_bf16(a[rt][ks], b1, accV[rt][1], 0, 0, 0);
      }
    }
#pragma unroll
    for (int rt = 0; rt < 4; ++rt) {
      int gA = blockIdx.x * WPB + rg * 32 + rt * 8 + kgrp * 2;
#pragma unroll
      for (int ct = 0; ct < 2; ++ct) {
        int h = g * 64 + cg * 32 + ct * 16 + lrow;
        float* o = out + gA * 1024 + h;
        o[0]    = at0[rt][0] * accV[rt][ct][0] + at0[rt][1] * accV[rt][ct][1];
        o[512]  = at0[rt][2] * accV[rt][ct][0] + at0[rt][3] * accV[rt][ct][1];
        o[1024] = at1[rt][0] * accV[rt][ct][2] + at1[rt][1] * accV[rt][ct][3];
        o[1536] = at1[rt][2] * accV[rt][ct][2] + at1[rt][3] * accV[rt][ct][3];
      }
    }
    if (t + 1 < 24) __syncthreads();
  }
}

extern "C" void kernel_launch(void* const* d_in, const int* in_sizes, int n_in,
                              void* d_out, int out_size, void* d_ws, size_t ws_size,
                              hipStream_t stream) {
  const float* charv = (const float*)d_in[0];
  const float* wordv = (const float*)d_in[1];
  const float* Wk = (const float*)d_in[2];
  const float* bk = (const float*)d_in[3];
  const float* Wq = (const float*)d_in[4];
  const float* bq = (const float*)d_in[5];
  const float* Wv = (const float*)d_in[6];
  const float* bv = (const float*)d_in[7];
  float* out = (float*)d_out;
  unsigned short* wt = (unsigned short*)d_ws;  // 1536*328*2 B

  prep_weights<<<(1536 * KP + 511) / 512, 512, 0, stream>>>(Wq, Wk, Wv, wt);

  const int lds_bytes = 2 * CHUNK_BYTES + 1536 * 4 + 1024 * 4 + 512 * 4;  // 96,256 B
  fused_attn<<<65536 / ROWS, 512, lds_bytes, stream>>>(charv, wordv, wt, bk, bq, bv, out);
}